// Round 1
// baseline (297.138 us; speedup 1.0000x reference)
//
#include <hip/hip_runtime.h>

// ACE symmetrizer: b[r,f,n] = sum_m cg[r,m] * A[f,m,n], for 5 A tensors,
// each contracted with a CG0 [8,M] and CG1 [24,M] in ONE pass over A.
//
// Memory-bound: ~499MB read + ~537MB write -> ~165us floor at 6.3TB/s.
// Structure: one block = one f and 512 consecutive n (256 thr x float2).
// CG coefficients are wave-uniform -> compiler emits s_load (scalar path),
// so each FMA is v_fmac_f32 acc, s_cg, v_a with no extra vmem/LDS issue.

template<int M>
__global__ __launch_bounds__(256)
void sym_kernel(const float* __restrict__ A,     // [F, M, N]
                const float* __restrict__ cg0,   // [8,  M]
                const float* __restrict__ cg1,   // [24, M]
                float* __restrict__ out0,        // [8,  F, N] flat
                float* __restrict__ out1,        // [24, F, N] flat
                int F, int N)
{
    const int nchunks = N >> 9;                 // N / (256 threads * 2 floats)
    const int bid = blockIdx.x;
    const int f   = bid / nchunks;
    const int nc  = bid - f * nchunks;
    const int n0  = (nc << 9) + ((int)threadIdx.x << 1);

    const float* a = A + (size_t)f * M * N + n0;

    float2 acc0[8], acc1[24];
#pragma unroll
    for (int r = 0; r < 8; ++r)  acc0[r] = make_float2(0.f, 0.f);
#pragma unroll
    for (int r = 0; r < 24; ++r) acc1[r] = make_float2(0.f, 0.f);

    for (int m = 0; m < M; ++m) {
        const float2 av = *reinterpret_cast<const float2*>(a + (size_t)m * N);
#pragma unroll
        for (int r = 0; r < 8; ++r) {
            const float c = cg0[r * M + m];     // wave-uniform -> s_load
            acc0[r].x = fmaf(c, av.x, acc0[r].x);
            acc0[r].y = fmaf(c, av.y, acc0[r].y);
        }
#pragma unroll
        for (int r = 0; r < 24; ++r) {
            const float c = cg1[r * M + m];     // wave-uniform -> s_load
            acc1[r].x = fmaf(c, av.x, acc1[r].x);
            acc1[r].y = fmaf(c, av.y, acc1[r].y);
        }
    }

    const size_t stride = (size_t)F * N;
    float* o0 = out0 + (size_t)f * N + n0;
#pragma unroll
    for (int r = 0; r < 8; ++r)
        *reinterpret_cast<float2*>(o0 + r * stride) = acc0[r];
    float* o1 = out1 + (size_t)f * N + n0;
#pragma unroll
    for (int r = 0; r < 24; ++r)
        *reinterpret_cast<float2*>(o1 + r * stride) = acc1[r];
}

template<int M>
static inline void launch_sym(const float* A, const float* cg0, const float* cg1,
                              float* out0, float* out1, int F, int N,
                              hipStream_t stream)
{
    const int nchunks = N >> 9;
    dim3 grid(F * nchunks), block(256);
    hipLaunchKernelGGL((sym_kernel<M>), grid, block, 0, stream,
                       A, cg0, cg1, out0, out1, F, N);
}

extern "C" void kernel_launch(void* const* d_in, const int* in_sizes, int n_in,
                              void* d_out, int out_size, void* d_ws, size_t ws_size,
                              hipStream_t stream)
{
    // Input order (setup_inputs dict order):
    // 0..4 : A2_l11[1024,9,1024], A2_l22[1024,25,1024], A2_l33[1024,49,1024],
    //        A3_l111[512,27,1024], A3_l211[512,45,1024]
    // 5..9 : CG0_* [8,M]   (same tuple order)
    // 10..14: CG1_* [24,M]
    const float* A0 = (const float*)d_in[0];
    const float* A1 = (const float*)d_in[1];
    const float* A2 = (const float*)d_in[2];
    const float* A3 = (const float*)d_in[3];
    const float* A4 = (const float*)d_in[4];

    const float* C0_0 = (const float*)d_in[5];
    const float* C0_1 = (const float*)d_in[6];
    const float* C0_2 = (const float*)d_in[7];
    const float* C0_3 = (const float*)d_in[8];
    const float* C0_4 = (const float*)d_in[9];

    const float* C1_0 = (const float*)d_in[10];
    const float* C1_1 = (const float*)d_in[11];
    const float* C1_2 = (const float*)d_in[12];
    const float* C1_3 = (const float*)d_in[13];
    const float* C1_4 = (const float*)d_in[14];

    float* out = (float*)d_out;

    const int N = 1024;
    // Output offsets (floats), return order: b0 tuple (5) then b1 tuple (5).
    // b0_i: 8*F_i*N ; b1_i: 24*F_i*N
    const size_t o0 = 0;                       // b0_2_l11  8*1024*1024
    const size_t o1 = o0 + (size_t)8  * 1024 * N;
    const size_t o2 = o1 + (size_t)8  * 1024 * N;
    const size_t o3 = o2 + (size_t)8  * 1024 * N;   // b0_3_l111 (F=512)
    const size_t o4 = o3 + (size_t)8  * 512  * N;
    const size_t o5 = o4 + (size_t)8  * 512  * N;   // b1_2_l11
    const size_t o6 = o5 + (size_t)24 * 1024 * N;
    const size_t o7 = o6 + (size_t)24 * 1024 * N;
    const size_t o8 = o7 + (size_t)24 * 1024 * N;   // b1_3_l111
    const size_t o9 = o8 + (size_t)24 * 512  * N;

    launch_sym<9> (A0, C0_0, C1_0, out + o0, out + o5, 1024, N, stream);
    launch_sym<25>(A1, C0_1, C1_1, out + o1, out + o6, 1024, N, stream);
    launch_sym<49>(A2, C0_2, C1_2, out + o2, out + o7, 1024, N, stream);
    launch_sym<27>(A3, C0_3, C1_3, out + o3, out + o8, 512,  N, stream);
    launch_sym<45>(A4, C0_4, C1_4, out + o4, out + o9, 512,  N, stream);
}

// Round 3
// 227.435 us; speedup vs baseline: 1.3065x; 1.3065x over previous
//
#include <hip/hip_runtime.h>

// ACE symmetrizer, fused: b[r,f,n] = sum_m cg[r,m] * A[f,m,n] for 5 (A, CG0, CG1)
// groups in ONE kernel. Memory-bound: 499MB read + 537MB write -> ~165us floor.
//
// Design:
//  - setup kernel transposes all CGs into d_ws as cgT[op][m][0..31] so the
//    32 per-m coefficients are 128 CONTIGUOUS bytes -> 2x s_load_dwordx16
//    (scalar path; v_fmac_f32 takes the coef as its one SGPR operand).
//  - main kernel: 256 threads, thread = 4 consecutive n (16B/lane native vec),
//    block = (op, f); covers full N=1024. Nontemporal loads/stores (zero reuse).
//  - 2-deep register prefetch on the m-loop; 128 fmacs per m hide latency.
//  - single dispatch -> one tail; shapes selected by uniform branch on blockIdx.

typedef float f32x4 __attribute__((ext_vector_type(4)));

#define NN 1024  // n-dim for every op

// float offsets into d_out (return order: b0 x5 then b1 x5)
#define O0_0 0UL
#define O0_1 8388608UL
#define O0_2 16777216UL
#define O0_3 25165824UL
#define O0_4 29360128UL
#define O1_0 33554432UL
#define O1_1 58720256UL
#define O1_2 83886080UL
#define O1_3 109051904UL
#define O1_4 121634816UL

// cgT float offsets in ws: 32*M per op, M = {9,25,49,27,45}
#define W_0 0
#define W_1 288
#define W_2 1088
#define W_3 2656
#define W_4 3520
#define W_TOT 4960

__global__ __launch_bounds__(256)
void cg_transpose(const float* __restrict__ c00, const float* __restrict__ c01,
                  const float* __restrict__ c02, const float* __restrict__ c03,
                  const float* __restrict__ c04,
                  const float* __restrict__ c10, const float* __restrict__ c11,
                  const float* __restrict__ c12, const float* __restrict__ c13,
                  const float* __restrict__ c14,
                  float* __restrict__ w)
{
    int t = blockIdx.x * 256 + threadIdx.x;
    if (t >= W_TOT) return;
    int M, off; const float* g0; const float* g1;
    if      (t < W_1) { M = 9;  off = W_0; g0 = c00; g1 = c10; }
    else if (t < W_2) { M = 25; off = W_1; g0 = c01; g1 = c11; }
    else if (t < W_3) { M = 49; off = W_2; g0 = c02; g1 = c12; }
    else if (t < W_4) { M = 27; off = W_3; g0 = c03; g1 = c13; }
    else              { M = 45; off = W_4; g0 = c04; g1 = c14; }
    int loc = t - off;
    int m = loc >> 5, r = loc & 31;
    w[t] = (r < 8) ? g0[r * M + m] : g1[(r - 8) * M + m];
}

__global__ __launch_bounds__(256)
void ace_sym_all(const float* __restrict__ A0, const float* __restrict__ A1,
                 const float* __restrict__ A2, const float* __restrict__ A3,
                 const float* __restrict__ A4,
                 const float* __restrict__ cgT, float* __restrict__ out)
{
    const int bid = blockIdx.x;

    const float* A; int M; int F; long f; size_t o0, o1; int cgo;
    if (bid < 1024)      { A = A0; M = 9;  F = 1024; f = bid;        o0 = O0_0; o1 = O1_0; cgo = W_0; }
    else if (bid < 2048) { A = A1; M = 25; F = 1024; f = bid - 1024; o0 = O0_1; o1 = O1_1; cgo = W_1; }
    else if (bid < 3072) { A = A2; M = 49; F = 1024; f = bid - 2048; o0 = O0_2; o1 = O1_2; cgo = W_2; }
    else if (bid < 3584) { A = A3; M = 27; F = 512;  f = bid - 3072; o0 = O0_3; o1 = O1_3; cgo = W_3; }
    else                 { A = A4; M = 45; F = 512;  f = bid - 3584; o0 = O0_4; o1 = O1_4; cgo = W_4; }

    const int n0 = (int)threadIdx.x * 4;
    const f32x4* ap = reinterpret_cast<const f32x4*>(A + (size_t)f * M * NN + n0);
    const float* cg = cgT + cgo;          // [M][32] contiguous per m

    f32x4 acc[32];
#pragma unroll
    for (int r = 0; r < 32; ++r) acc[r] = (f32x4)(0.f);

    f32x4 cur = __builtin_nontemporal_load(ap);
    for (int m = 0; m < M - 1; ++m) {
        const f32x4 nxt = __builtin_nontemporal_load(ap + (size_t)(m + 1) * (NN / 4));
        const float* c = cg + m * 32;     // uniform -> s_load_dwordx16 x2
#pragma unroll
        for (int r = 0; r < 32; ++r) {
            const float cr = c[r];
            acc[r].x = fmaf(cr, cur.x, acc[r].x);
            acc[r].y = fmaf(cr, cur.y, acc[r].y);
            acc[r].z = fmaf(cr, cur.z, acc[r].z);
            acc[r].w = fmaf(cr, cur.w, acc[r].w);
        }
        cur = nxt;
    }
    {
        const float* c = cg + (M - 1) * 32;
#pragma unroll
        for (int r = 0; r < 32; ++r) {
            const float cr = c[r];
            acc[r].x = fmaf(cr, cur.x, acc[r].x);
            acc[r].y = fmaf(cr, cur.y, acc[r].y);
            acc[r].z = fmaf(cr, cur.z, acc[r].z);
            acc[r].w = fmaf(cr, cur.w, acc[r].w);
        }
    }

    const size_t stride = (size_t)F * NN;
    float* p0 = out + o0 + (size_t)f * NN + n0;
#pragma unroll
    for (int r = 0; r < 8; ++r)
        __builtin_nontemporal_store(acc[r], reinterpret_cast<f32x4*>(p0 + r * stride));
    float* p1 = out + o1 + (size_t)f * NN + n0;
#pragma unroll
    for (int r = 0; r < 24; ++r)
        __builtin_nontemporal_store(acc[8 + r], reinterpret_cast<f32x4*>(p1 + r * stride));
}

extern "C" void kernel_launch(void* const* d_in, const int* in_sizes, int n_in,
                              void* d_out, int out_size, void* d_ws, size_t ws_size,
                              hipStream_t stream)
{
    const float* A0 = (const float*)d_in[0];
    const float* A1 = (const float*)d_in[1];
    const float* A2 = (const float*)d_in[2];
    const float* A3 = (const float*)d_in[3];
    const float* A4 = (const float*)d_in[4];

    float* wsT = (float*)d_ws;

    hipLaunchKernelGGL(cg_transpose, dim3((W_TOT + 255) / 256), dim3(256), 0, stream,
                       (const float*)d_in[5], (const float*)d_in[6], (const float*)d_in[7],
                       (const float*)d_in[8], (const float*)d_in[9],
                       (const float*)d_in[10], (const float*)d_in[11], (const float*)d_in[12],
                       (const float*)d_in[13], (const float*)d_in[14], wsT);

    hipLaunchKernelGGL(ace_sym_all, dim3(4096), dim3(256), 0, stream,
                       A0, A1, A2, A3, A4, (const float*)wsT, (float*)d_out);
}

// Round 4
// 217.939 us; speedup vs baseline: 1.3634x; 1.0436x over previous
//
#include <hip/hip_runtime.h>

// ACE symmetrizer, fused: b[r,f,n] = sum_m cg[r,m] * A[f,m,n] for 5 (A, CG0, CG1)
// groups in ONE kernel. Memory-bound: 499MB read + 537MB write -> ~165us floor.
//
// Round-4 changes vs round-3 (227us):
//  - compile-time M per branch (5 inlined template bodies, uniform bid branch)
//  - 4-deep prefetch rotation: 4 x 1KB loads in flight per wave (was 1) to
//    cover ~900cyc HBM latency; buf[] statically indexed (full inner unroll)
//  - cgT zero-padded to MP=ceil(M/4)*4 and A row clamped to M-1 -> clean
//    4x-unrolled loop, no remainder (0-coef fmas on clamped real data = exact)
//  - heavy ops (M=49,45) scheduled first to shrink the tail

typedef float f32x4 __attribute__((ext_vector_type(4)));

#define NN 1024

// output float offsets (return order: b0 x5 then b1 x5)
#define O0_0 0UL
#define O0_1 8388608UL
#define O0_2 16777216UL
#define O0_3 25165824UL
#define O0_4 29360128UL
#define O1_0 33554432UL
#define O1_1 58720256UL
#define O1_2 83886080UL
#define O1_3 109051904UL
#define O1_4 121634816UL

// padded cgT float offsets in ws: 32*MP per op, MP = {12,28,52,28,48}
#define WP_0 0
#define WP_1 384
#define WP_2 1280
#define WP_3 2944
#define WP_4 3840
#define WP_TOT 5376

__global__ __launch_bounds__(256)
void cg_transpose(const float* __restrict__ c00, const float* __restrict__ c01,
                  const float* __restrict__ c02, const float* __restrict__ c03,
                  const float* __restrict__ c04,
                  const float* __restrict__ c10, const float* __restrict__ c11,
                  const float* __restrict__ c12, const float* __restrict__ c13,
                  const float* __restrict__ c14,
                  float* __restrict__ w)
{
    int t = blockIdx.x * 256 + threadIdx.x;
    if (t >= WP_TOT) return;
    int M, off; const float* g0; const float* g1;
    if      (t < WP_1) { M = 9;  off = WP_0; g0 = c00; g1 = c10; }
    else if (t < WP_2) { M = 25; off = WP_1; g0 = c01; g1 = c11; }
    else if (t < WP_3) { M = 49; off = WP_2; g0 = c02; g1 = c12; }
    else if (t < WP_4) { M = 27; off = WP_3; g0 = c03; g1 = c13; }
    else               { M = 45; off = WP_4; g0 = c04; g1 = c14; }
    int loc = t - off;
    int m = loc >> 5, r = loc & 31;
    float v = 0.f;
    if (m < M) v = (r < 8) ? g0[r * M + m] : g1[(r - 8) * M + m];
    w[t] = v;
}

template<int M, int MP>
__device__ __forceinline__ void run_op(const float* __restrict__ Af,  // A + f*M*NN + n0
                                       const float* __restrict__ cg,  // cgT + WP_op, [MP][32]
                                       float* __restrict__ p0,        // out + o0 + f*NN + n0
                                       float* __restrict__ p1,        // out + o1 + f*NN + n0
                                       size_t stride)                 // F*NN
{
    const f32x4* ap = reinterpret_cast<const f32x4*>(Af);

    f32x4 buf[4];
#pragma unroll
    for (int i = 0; i < 4; ++i) {
        const int mi = (i < M) ? i : (M - 1);
        buf[i] = __builtin_nontemporal_load(ap + (size_t)mi * (NN / 4));
    }

    f32x4 acc[32];
#pragma unroll
    for (int r = 0; r < 32; ++r) acc[r] = (f32x4)(0.f);

#pragma unroll 1
    for (int m = 0; m < MP; m += 4) {
#pragma unroll
        for (int i = 0; i < 4; ++i) {
            const f32x4 cur = buf[i];
            int nm = m + 4 + i;
            nm = (nm < M) ? nm : (M - 1);     // clamped prefetch (L1-hit, harmless)
            buf[i] = __builtin_nontemporal_load(ap + (size_t)nm * (NN / 4));
            const float* c = cg + (size_t)(m + i) * 32;   // uniform -> s_load x2
#pragma unroll
            for (int r = 0; r < 32; ++r) {
                const float cr = c[r];
                acc[r].x = fmaf(cr, cur.x, acc[r].x);
                acc[r].y = fmaf(cr, cur.y, acc[r].y);
                acc[r].z = fmaf(cr, cur.z, acc[r].z);
                acc[r].w = fmaf(cr, cur.w, acc[r].w);
            }
        }
    }

#pragma unroll
    for (int r = 0; r < 8; ++r)
        __builtin_nontemporal_store(acc[r], reinterpret_cast<f32x4*>(p0 + r * stride));
#pragma unroll
    for (int r = 0; r < 24; ++r)
        __builtin_nontemporal_store(acc[8 + r], reinterpret_cast<f32x4*>(p1 + r * stride));
}

__global__ __launch_bounds__(256)
void ace_sym_all(const float* __restrict__ A0, const float* __restrict__ A1,
                 const float* __restrict__ A2, const float* __restrict__ A3,
                 const float* __restrict__ A4,
                 const float* __restrict__ cgT, float* __restrict__ out)
{
    const int bid = blockIdx.x;
    const int n0 = (int)threadIdx.x * 4;

    // heavy-first: M=49 (F=1024), M=45 (512), M=25 (1024), M=27 (512), M=9 (1024)
    if (bid < 1024) {
        const size_t f = bid;
        run_op<49, 52>(A2 + f * 49 * NN + n0, cgT + WP_2,
                       out + O0_2 + f * NN + n0, out + O1_2 + f * NN + n0,
                       (size_t)1024 * NN);
    } else if (bid < 1536) {
        const size_t f = bid - 1024;
        run_op<45, 48>(A4 + f * 45 * NN + n0, cgT + WP_4,
                       out + O0_4 + f * NN + n0, out + O1_4 + f * NN + n0,
                       (size_t)512 * NN);
    } else if (bid < 2560) {
        const size_t f = bid - 1536;
        run_op<25, 28>(A1 + f * 25 * NN + n0, cgT + WP_1,
                       out + O0_1 + f * NN + n0, out + O1_1 + f * NN + n0,
                       (size_t)1024 * NN);
    } else if (bid < 3072) {
        const size_t f = bid - 2560;
        run_op<27, 28>(A3 + f * 27 * NN + n0, cgT + WP_3,
                       out + O0_3 + f * NN + n0, out + O1_3 + f * NN + n0,
                       (size_t)512 * NN);
    } else {
        const size_t f = bid - 3072;
        run_op<9, 12>(A0 + f * 9 * NN + n0, cgT + WP_0,
                      out + O0_0 + f * NN + n0, out + O1_0 + f * NN + n0,
                      (size_t)1024 * NN);
    }
}

extern "C" void kernel_launch(void* const* d_in, const int* in_sizes, int n_in,
                              void* d_out, int out_size, void* d_ws, size_t ws_size,
                              hipStream_t stream)
{
    const float* A0 = (const float*)d_in[0];
    const float* A1 = (const float*)d_in[1];
    const float* A2 = (const float*)d_in[2];
    const float* A3 = (const float*)d_in[3];
    const float* A4 = (const float*)d_in[4];

    float* wsT = (float*)d_ws;

    hipLaunchKernelGGL(cg_transpose, dim3((WP_TOT + 255) / 256), dim3(256), 0, stream,
                       (const float*)d_in[5], (const float*)d_in[6], (const float*)d_in[7],
                       (const float*)d_in[8], (const float*)d_in[9],
                       (const float*)d_in[10], (const float*)d_in[11], (const float*)d_in[12],
                       (const float*)d_in[13], (const float*)d_in[14], wsT);

    hipLaunchKernelGGL(ace_sym_all, dim3(4096), dim3(256), 0, stream,
                       A0, A1, A2, A3, A4, (const float*)wsT, (float*)d_out);
}